// Round 1
// baseline (1306.226 us; speedup 1.0000x reference)
//
#include <hip/hip_runtime.h>
#include <hip/hip_bf16.h>

// ---------------------------------------------------------------------------
// GAT fraud detector: 3x (GEMM -> attention aggregate -> BN -> ReLU) -> pool -> MLP
// N=50000 nodes, E=800000 edges, Fin=128, heads=4, Hd=64, wdim=256.
// Strategy: build CSR-by-dst once per call; per-node block does softmax+gather
// (no scatter atomics). fp32 everywhere this round (correctness baseline).
// ---------------------------------------------------------------------------

#define NEG_SLOPE 0.2f
#define BN_EPS 1e-5f

// ---------------- CSR construction ----------------

__global__ void hist_kernel(const int* __restrict__ ei, int* __restrict__ deg, int E) {
    int e = blockIdx.x * blockDim.x + threadIdx.x;
    if (e < E) atomicAdd(&deg[ei[E + e]], 1);   // dst = ei[E+e]
}

__global__ void scan_kernel(const int* __restrict__ deg, int* __restrict__ offsets,
                            int* __restrict__ cursor, int N) {
    __shared__ int tmp[1024];
    int t = threadIdx.x;
    int carry = 0;
    for (int base = 0; base < N; base += 1024) {
        __syncthreads();
        int i = base + t;
        int v = (i < N) ? deg[i] : 0;
        tmp[t] = v;
        __syncthreads();
        for (int off = 1; off < 1024; off <<= 1) {
            int y = (t >= off) ? tmp[t - off] : 0;
            __syncthreads();
            tmp[t] += y;
            __syncthreads();
        }
        int incl = tmp[t];
        int excl = incl - v;
        if (i < N) { offsets[i] = carry + excl; cursor[i] = carry + excl; }
        int total = tmp[1023];
        carry += total;
    }
    if (t == 0) offsets[N] = carry;
}

__global__ void scatter_kernel(const int* __restrict__ ei, int* __restrict__ cursor,
                               int* __restrict__ srcs, int E) {
    int e = blockIdx.x * blockDim.x + threadIdx.x;
    if (e < E) {
        int s = ei[e];
        int d = ei[E + e];
        int p = atomicAdd(&cursor[d], 1);
        srcs[p] = s;
    }
}

// ---------------- fp32 tiled GEMM: C[M,Nn] = A[M,K] @ B[K,Nn] ----------------
// 64x64 tile, BK=16, 256 threads, 4x4 microtile per thread.

__launch_bounds__(256)
__global__ void sgemm_kernel(const float* __restrict__ A, const float* __restrict__ B,
                             float* __restrict__ C, int M, int K, int Nn) {
    __shared__ float As[16][68];   // As[k][m]
    __shared__ float Bs[16][68];   // Bs[k][n]
    int t = threadIdx.x;
    int row0 = blockIdx.x * 64;
    int col0 = blockIdx.y * 64;
    int ty = t >> 4, tx = t & 15;

    int am = t >> 2;            // 0..63  (A tile row)
    int ak = (t & 3) * 4;       // 0..12  (A tile col base)
    int bk = t >> 4;            // 0..15  (B tile row)
    int bn = (t & 15) * 4;      // 0..60  (B tile col base)
    int arow = row0 + am;
    bool avalid = arow < M;

    float acc[4][4] = {};

    for (int kt = 0; kt < K; kt += 16) {
        float4 a4 = avalid ? *(const float4*)&A[(size_t)arow * K + kt + ak]
                           : make_float4(0.f, 0.f, 0.f, 0.f);
        float4 b4 = *(const float4*)&B[(size_t)(kt + bk) * Nn + col0 + bn];
        As[ak + 0][am] = a4.x; As[ak + 1][am] = a4.y;
        As[ak + 2][am] = a4.z; As[ak + 3][am] = a4.w;
        *(float4*)&Bs[bk][bn] = b4;
        __syncthreads();
#pragma unroll
        for (int kk = 0; kk < 16; ++kk) {
            float a[4], b[4];
#pragma unroll
            for (int i = 0; i < 4; ++i) a[i] = As[kk][ty * 4 + i];
#pragma unroll
            for (int j = 0; j < 4; ++j) b[j] = Bs[kk][tx * 4 + j];
#pragma unroll
            for (int i = 0; i < 4; ++i)
#pragma unroll
                for (int j = 0; j < 4; ++j) acc[i][j] = fmaf(a[i], b[j], acc[i][j]);
        }
        __syncthreads();
    }

#pragma unroll
    for (int i = 0; i < 4; ++i) {
        int r = row0 + ty * 4 + i;
        if (r < M) {
            float4 v = make_float4(acc[i][0], acc[i][1], acc[i][2], acc[i][3]);
            *(float4*)&C[(size_t)r * Nn + col0 + tx * 4] = v;
        }
    }
}

// ---------------- per-node attention coefficients s,d ----------------
// s[i,h] = sum_c h[i,h,c]*asrc[h,c];  d likewise. One wave per node iteration.

__global__ void sd_kernel(const float* __restrict__ hbuf, const float* __restrict__ asrc,
                          const float* __restrict__ adst, float* __restrict__ sv,
                          float* __restrict__ dv, int N, int H) {
    int gid = blockIdx.x * blockDim.x + threadIdx.x;
    int wid = gid >> 6;
    int lane = threadIdx.x & 63;
    int nwaves = (gridDim.x * blockDim.x) >> 6;
    int HC = H * 64;
    for (int i = wid; i < N; i += nwaves) {
        for (int h = 0; h < H; ++h) {
            float v = hbuf[(size_t)i * HC + h * 64 + lane];
            float s = v * asrc[h * 64 + lane];
            float d = v * adst[h * 64 + lane];
#pragma unroll
            for (int m = 32; m >= 1; m >>= 1) {
                s += __shfl_xor(s, m, 64);
                d += __shfl_xor(d, m, 64);
            }
            if (lane == 0) { sv[i * H + h] = s; dv[i * H + h] = d; }
        }
    }
}

// ---------------- attention aggregation (softmax over incoming edges) ----------------
// One block per dst node. blockDim = H*64. Wave w owns head w (max/denom via shuffles).
// Self-loop included implicitly. out[i,:] = sum_e alpha_e * h[src_e,:] + bias.

template <int H>
__launch_bounds__(256)
__global__ void aggregate_kernel(const float* __restrict__ hbuf, const float* __restrict__ sv,
                                 const float* __restrict__ dv, const int* __restrict__ offsets,
                                 const int* __restrict__ srcs, const float* __restrict__ bias,
                                 float* __restrict__ outbuf, int N) {
    const int HC = H * 64;
    int i = blockIdx.x;
    if (i >= N) return;
    int t = threadIdx.x;
    int h = t >> 6;          // wave id == head
    int lane = t & 63;

    int beg = offsets[i];
    int end = offsets[i + 1];

    float d_i = dv[i * H + h];
    float s_i = sv[i * H + h];
    float e_self = s_i + d_i;
    e_self = e_self > 0.f ? e_self : NEG_SLOPE * e_self;

    // pass 1: max per head (wave-parallel over edges)
    float mx = e_self;
    for (int j = beg + lane; j < end; j += 64) {
        int srcn = srcs[j];
        float e = sv[srcn * H + h] + d_i;
        e = e > 0.f ? e : NEG_SLOPE * e;
        mx = fmaxf(mx, e);
    }
#pragma unroll
    for (int m = 32; m >= 1; m >>= 1) mx = fmaxf(mx, __shfl_xor(mx, m, 64));

    // pass 2: denominator
    float den = 0.f;
    for (int j = beg + lane; j < end; j += 64) {
        int srcn = srcs[j];
        float e = sv[srcn * H + h] + d_i;
        e = e > 0.f ? e : NEG_SLOPE * e;
        den += __expf(e - mx);
    }
#pragma unroll
    for (int m = 32; m >= 1; m >>= 1) den += __shfl_xor(den, m, 64);
    float w_self = __expf(e_self - mx);
    den += w_self;
    den += 1e-16f;

    // pass 3: gather-accumulate weighted h rows (block-uniform edge loop)
    float acc = w_self * hbuf[(size_t)i * HC + t];
    int j = beg;
    int srcn_next = (j < end) ? srcs[j] : 0;
    for (; j < end; ) {
        int srcn = srcn_next;
        float sval = sv[srcn * H + h];
        ++j;
        if (j < end) srcn_next = srcs[j];
        float e = sval + d_i;
        e = e > 0.f ? e : NEG_SLOPE * e;
        float w = __expf(e - mx);
        acc += w * hbuf[(size_t)srcn * HC + t];
    }
    outbuf[(size_t)i * HC + t] = acc / den + bias[t];
}

// ---------------- BatchNorm ----------------

__global__ void bn_stats_kernel(const float* __restrict__ x, float* __restrict__ sums,
                                float* __restrict__ sumsq, int N, int F) {
    int t = threadIdx.x;
    int col = t % F;
    int rg = t / F;
    int RG = blockDim.x / F;
    int rows_per = (N + gridDim.x - 1) / gridDim.x;
    int r0 = blockIdx.x * rows_per;
    int r1 = min(N, r0 + rows_per);
    float s = 0.f, q = 0.f;
    for (int r = r0 + rg; r < r1; r += RG) {
        float v = x[(size_t)r * F + col];
        s += v; q += v * v;
    }
    __shared__ float ls[256], lq[256];
    ls[t] = s; lq[t] = q;
    __syncthreads();
    if (t < F) {
        for (int g = 1; g < RG; ++g) { s += ls[t + g * F]; q += lq[t + g * F]; }
        atomicAdd(&sums[t], s);
        atomicAdd(&sumsq[t], q);
    }
}

__global__ void bn_final_kernel(const float* __restrict__ sums, const float* __restrict__ sumsq,
                                const float* __restrict__ g, const float* __restrict__ be,
                                float* __restrict__ scale, float* __restrict__ shift,
                                int N, int F) {
    int t = threadIdx.x;
    if (t < F) {
        float mean = sums[t] / (float)N;
        float var = sumsq[t] / (float)N - mean * mean;
        float sc = g[t] * rsqrtf(var + BN_EPS);
        scale[t] = sc;
        shift[t] = be[t] - sc * mean;
    }
}

__global__ void bn_apply_kernel(float* __restrict__ x, const float* __restrict__ scale,
                                const float* __restrict__ shift, int total, int Fmask) {
    int i = blockIdx.x * blockDim.x + threadIdx.x;
    if (i < total) {
        int col = i & Fmask;
        float v = x[i] * scale[col] + shift[col];
        x[i] = v > 0.f ? v : 0.f;
    }
}

// ---------------- pooling + classifier ----------------

__global__ void pool_kernel(const float* __restrict__ x, float* __restrict__ psum,
                            float* __restrict__ pmax, int N, int F) {
    int t = threadIdx.x;
    int col = t % F;
    int rg = t / F;
    int RG = blockDim.x / F;
    int rows_per = (N + gridDim.x - 1) / gridDim.x;
    int r0 = blockIdx.x * rows_per;
    int r1 = min(N, r0 + rows_per);
    float s = 0.f, m = 0.f;   // values are post-ReLU, >= 0
    for (int r = r0 + rg; r < r1; r += RG) {
        float v = x[(size_t)r * F + col];
        s += v; m = fmaxf(m, v);
    }
    __shared__ float ls[256], lm[256];
    ls[t] = s; lm[t] = m;
    __syncthreads();
    if (t < F) {
        for (int g = 1; g < RG; ++g) { s += ls[t + g * F]; m = fmaxf(m, lm[t + g * F]); }
        atomicAdd(&psum[t], s);
        atomicMax((unsigned int*)&pmax[t], __float_as_uint(m));
    }
}

__global__ void classify_kernel(const float* __restrict__ psum, const float* __restrict__ pmax,
                                const float* __restrict__ Wc1, const float* __restrict__ bc1,
                                const float* __restrict__ Wc2, const float* __restrict__ bc2,
                                float* __restrict__ out, int N) {
    __shared__ float pooled[128];
    __shared__ float z[64];
    int t = threadIdx.x;   // 128 threads
    if (t < 64) pooled[t] = psum[t] / (float)N;
    else pooled[t] = pmax[t - 64];
    __syncthreads();
    if (t < 64) {
        float a = bc1[t];
        for (int k = 0; k < 128; ++k) a += pooled[k] * Wc1[k * 64 + t];
        z[t] = a > 0.f ? a : 0.f;
    }
    __syncthreads();
    if (t < 2) {
        float a = bc2[t];
        for (int j = 0; j < 64; ++j) a += z[j] * Wc2[j * 2 + t];
        out[t] = a;
    }
}

// ---------------- driver ----------------

extern "C" void kernel_launch(void* const* d_in, const int* in_sizes, int n_in,
                              void* d_out, int out_size, void* d_ws, size_t ws_size,
                              hipStream_t stream) {
    const float* x   = (const float*)d_in[0];
    const int*   ei  = (const int*)d_in[1];
    const float* W0  = (const float*)d_in[2];  const float* b0  = (const float*)d_in[3];
    const float* as0 = (const float*)d_in[4];  const float* ad0 = (const float*)d_in[5];
    const float* g0  = (const float*)d_in[6];  const float* be0 = (const float*)d_in[7];
    const float* W1  = (const float*)d_in[8];  const float* b1  = (const float*)d_in[9];
    const float* as1 = (const float*)d_in[10]; const float* ad1 = (const float*)d_in[11];
    const float* g1  = (const float*)d_in[12]; const float* be1 = (const float*)d_in[13];
    const float* W2  = (const float*)d_in[14]; const float* b2  = (const float*)d_in[15];
    const float* as2 = (const float*)d_in[16]; const float* ad2 = (const float*)d_in[17];
    const float* g2  = (const float*)d_in[18]; const float* be2 = (const float*)d_in[19];
    const float* Wc1 = (const float*)d_in[20]; const float* bc1 = (const float*)d_in[21];
    const float* Wc2 = (const float*)d_in[22]; const float* bc2 = (const float*)d_in[23];
    float* out = (float*)d_out;

    const int N = in_sizes[0] / 128;   // 50000
    const int E = in_sizes[1] / 2;     // 800000

    // workspace carve-up (256B aligned regions)
    char* ws = (char*)d_ws;
    size_t o = 0;
    auto alloc = [&](size_t bytes) -> void* {
        void* p = ws + o;
        o = (o + bytes + 255) & ~(size_t)255;
        return p;
    };
    int*   deg     = (int*)alloc((size_t)N * 4);
    int*   offsets = (int*)alloc((size_t)(N + 1) * 4);
    int*   cursor  = (int*)alloc((size_t)N * 4);
    int*   srcs    = (int*)alloc((size_t)E * 4);
    float* buf1    = (float*)alloc((size_t)N * 256 * 4);
    float* buf2    = (float*)alloc((size_t)N * 256 * 4);
    float* sv      = (float*)alloc((size_t)N * 4 * 4);
    float* dv      = (float*)alloc((size_t)N * 4 * 4);
    float* bnsum   = (float*)alloc(256 * 4);
    float* bnsq    = (float*)alloc(256 * 4);
    float* scale   = (float*)alloc(256 * 4);
    float* shift   = (float*)alloc(256 * 4);
    float* psum    = (float*)alloc(64 * 4);
    float* pmax    = (float*)alloc(64 * 4);

    // ---- CSR by destination (reused by all 3 layers) ----
    hipMemsetAsync(deg, 0, (size_t)N * 4, stream);
    int eb = (E + 255) / 256;
    hist_kernel<<<eb, 256, 0, stream>>>(ei, deg, E);
    scan_kernel<<<1, 1024, 0, stream>>>(deg, offsets, cursor, N);
    scatter_kernel<<<eb, 256, 0, stream>>>(ei, cursor, srcs, E);

    auto run_layer = [&](const float* in, int K, const float* W, int F, const float* bias,
                         const float* asrc, const float* adst, int H,
                         const float* gamma, const float* beta) {
        dim3 gg((N + 63) / 64, F / 64);
        sgemm_kernel<<<gg, 256, 0, stream>>>(in, W, buf1, N, K, F);
        sd_kernel<<<512, 256, 0, stream>>>(buf1, asrc, adst, sv, dv, N, H);
        if (H == 4)
            aggregate_kernel<4><<<N, 256, 0, stream>>>(buf1, sv, dv, offsets, srcs, bias, buf2, N);
        else
            aggregate_kernel<1><<<N, 64, 0, stream>>>(buf1, sv, dv, offsets, srcs, bias, buf2, N);
        hipMemsetAsync(bnsum, 0, F * 4, stream);
        hipMemsetAsync(bnsq, 0, F * 4, stream);
        bn_stats_kernel<<<256, 256, 0, stream>>>(buf2, bnsum, bnsq, N, F);
        bn_final_kernel<<<1, F, 0, stream>>>(bnsum, bnsq, gamma, beta, scale, shift, N, F);
        int total = N * F;
        bn_apply_kernel<<<(total + 255) / 256, 256, 0, stream>>>(buf2, scale, shift, total, F - 1);
    };

    // layer 0: x[N,128] -> buf2[N,256]
    run_layer(x, 128, W0, 256, b0, as0, ad0, 4, g0, be0);
    // layer 1: buf2[N,256] -> buf2[N,256]
    run_layer(buf2, 256, W1, 256, b1, as1, ad1, 4, g1, be1);
    // layer 2: buf2[N,256] -> buf2[N,64] (1 head, no concat)
    run_layer(buf2, 256, W2, 64, b2, as2, ad2, 1, g2, be2);

    // pooling + classifier
    hipMemsetAsync(psum, 0, 64 * 4, stream);
    hipMemsetAsync(pmax, 0, 64 * 4, stream);
    pool_kernel<<<256, 256, 0, stream>>>(buf2, psum, pmax, N, 64);
    classify_kernel<<<1, 128, 0, stream>>>(psum, pmax, Wc1, bc1, Wc2, bc2, out, N);
}

// Round 2
// 874.874 us; speedup vs baseline: 1.4930x; 1.4930x over previous
//
#include <hip/hip_runtime.h>

// ---------------------------------------------------------------------------
// GAT fraud detector, round 2: bf16 storage + MFMA GEMM.
// Pipeline per layer: MFMA bf16 GEMM (h, bf16) -> sd coeffs (fp32) ->
// CSR softmax-aggregate (bf16 gathers, fp32 accum, bf16 out) -> BN+ReLU (bf16).
// ---------------------------------------------------------------------------

typedef unsigned int uint;
typedef unsigned short ushort;

#define NEG_SLOPE 0.2f
#define BN_EPS 1e-5f

__device__ __forceinline__ float bf2f(uint u) { return __uint_as_float(u << 16); }
__device__ __forceinline__ ushort f2bf(float f) {
    uint u = __float_as_uint(f);
    u += 0x7fff + ((u >> 16) & 1);   // round-nearest-even
    return (ushort)(u >> 16);
}
__device__ __forceinline__ float lrelu(float x) { return x > 0.f ? x : NEG_SLOPE * x; }

// ---------------- CSR construction ----------------

__global__ void hist_kernel(const int* __restrict__ ei, int* __restrict__ deg, int E) {
    int e = blockIdx.x * blockDim.x + threadIdx.x;
    if (e < E) atomicAdd(&deg[ei[E + e]], 1);
}

__global__ void scan_kernel(const int* __restrict__ deg, int* __restrict__ offsets,
                            int* __restrict__ cursor, int N) {
    __shared__ int tmp[1024];
    int t = threadIdx.x;
    int carry = 0;
    for (int base = 0; base < N; base += 1024) {
        __syncthreads();
        int i = base + t;
        int v = (i < N) ? deg[i] : 0;
        tmp[t] = v;
        __syncthreads();
        for (int off = 1; off < 1024; off <<= 1) {
            int y = (t >= off) ? tmp[t - off] : 0;
            __syncthreads();
            tmp[t] += y;
            __syncthreads();
        }
        int incl = tmp[t];
        int excl = incl - v;
        if (i < N) { offsets[i] = carry + excl; cursor[i] = carry + excl; }
        carry += tmp[1023];
    }
    if (t == 0) offsets[N] = carry;
}

__global__ void scatter_kernel(const int* __restrict__ ei, int* __restrict__ cursor,
                               int* __restrict__ srcs, int E) {
    int e = blockIdx.x * blockDim.x + threadIdx.x;
    if (e < E) {
        int s = ei[e];
        int d = ei[E + e];
        int p = atomicAdd(&cursor[d], 1);
        srcs[p] = s;
    }
}

// ---------------- conversions ----------------

__global__ void cvt_x_kernel(const float* __restrict__ x, ushort* __restrict__ xb,
                             int total_real, int total_pad) {
    int i = blockIdx.x * blockDim.x + threadIdx.x;
    if (i < total_pad) xb[i] = (i < total_real) ? f2bf(x[i]) : (ushort)0;
}

// Wt[n*K + k] = bf16(W[k*F + n]);  W is [K,F] row-major.
__global__ void transpose_w_kernel(const float* __restrict__ W, ushort* __restrict__ Wt,
                                   int K, int F) {
    int i = blockIdx.x * blockDim.x + threadIdx.x;
    if (i < K * F) {
        int n = i / K, k = i - n * K;
        Wt[i] = f2bf(W[(size_t)k * F + n]);
    }
}

// ---------------- bf16 MFMA GEMM: C[M,Nn] = A[M,K] @ Bt[Nn,K]^T ----------------
// BM=128 rows x BN cols per block, 256 threads (4 waves), BK=32.
// global_load_lds width-16 staging; mfma_f32_16x16x32_bf16.

typedef __attribute__((ext_vector_type(8))) short bf16x8;
typedef __attribute__((ext_vector_type(4))) float floatx4;

template <int BN>
__launch_bounds__(256)
__global__ void mfma_gemm_bt(const ushort* __restrict__ A, const ushort* __restrict__ Bt,
                             ushort* __restrict__ C, int K, int Nn) {
    constexpr int WCOLS = (BN == 128) ? 2 : 1;       // waves along N
    constexpr int WROWS = 4 / WCOLS;                 // waves along M
    constexpr int MT = 128 / (WROWS * 16);           // 16x16 tiles per wave (M)
    constexpr int NT = BN / (WCOLS * 16);            // 16x16 tiles per wave (N)
    constexpr int BCALLS = (BN * 32 * 2) / 4096;     // global_load_lds calls for B

    __shared__ ushort As[128 * 32];
    __shared__ ushort Bs[BN * 32];

    int t = threadIdx.x;
    int w = t >> 6, l = t & 63;
    int row0 = blockIdx.x * 128;
    int col0 = blockIdx.y * BN;
    int wr = (w / WCOLS) * (MT * 16);
    int wc = (w % WCOLS) * (NT * 16);

    floatx4 acc[MT][NT];
#pragma unroll
    for (int mi = 0; mi < MT; ++mi)
#pragma unroll
        for (int ni = 0; ni < NT; ++ni)
#pragma unroll
            for (int r = 0; r < 4; ++r) acc[mi][ni][r] = 0.f;

    int mrow = l & 15;
    int kc = (l >> 4) * 8;

    for (int kt = 0; kt < K; kt += 32) {
        // stage A tile: 128 rows x 32 k (8 KB) = 2 calls x 4 waves x 1 KB
#pragma unroll
        for (int c = 0; c < 2; ++c) {
            int idx = c * 256 + t;                       // 0..511
            const ushort* gp = A + (size_t)(row0 + (idx >> 2)) * K + kt + (idx & 3) * 8;
            __builtin_amdgcn_global_load_lds(
                (const __attribute__((address_space(1))) void*)gp,
                (__attribute__((address_space(3))) void*)(As + (idx & ~63) * 8),
                16, 0, 0);
        }
        // stage B tile: BN rows x 32 k
#pragma unroll
        for (int c = 0; c < BCALLS; ++c) {
            int idx = c * 256 + t;
            const ushort* gp = Bt + (size_t)(col0 + (idx >> 2)) * K + kt + (idx & 3) * 8;
            __builtin_amdgcn_global_load_lds(
                (const __attribute__((address_space(1))) void*)gp,
                (__attribute__((address_space(3))) void*)(Bs + (idx & ~63) * 8),
                16, 0, 0);
        }
        __syncthreads();

        bf16x8 af[MT], bfr[NT];
#pragma unroll
        for (int mi = 0; mi < MT; ++mi)
            af[mi] = *(const bf16x8*)&As[(wr + mi * 16 + mrow) * 32 + kc];
#pragma unroll
        for (int ni = 0; ni < NT; ++ni)
            bfr[ni] = *(const bf16x8*)&Bs[(wc + ni * 16 + mrow) * 32 + kc];
#pragma unroll
        for (int mi = 0; mi < MT; ++mi)
#pragma unroll
            for (int ni = 0; ni < NT; ++ni)
                acc[mi][ni] = __builtin_amdgcn_mfma_f32_16x16x32_bf16(
                    af[mi], bfr[ni], acc[mi][ni], 0, 0, 0);
        __syncthreads();
    }

    // epilogue: C/D layout col=lane&15, row=(lane>>4)*4+reg (m89-verified)
#pragma unroll
    for (int mi = 0; mi < MT; ++mi) {
        int rbase = row0 + wr + mi * 16 + (l >> 4) * 4;
#pragma unroll
        for (int ni = 0; ni < NT; ++ni) {
            int col = col0 + wc + ni * 16 + (l & 15);
#pragma unroll
            for (int r = 0; r < 4; ++r)
                C[(size_t)(rbase + r) * Nn + col] = f2bf(acc[mi][ni][r]);
        }
    }
}

// ---------------- attention coefficients ----------------
// H=4: wave per node, lane owns 4 channels (asrc flat index == global channel).

__global__ void sd4_kernel(const ushort* __restrict__ hb, const float* __restrict__ asrc,
                           const float* __restrict__ adst, float* __restrict__ sv,
                           float* __restrict__ dv, int N) {
    int gid = blockIdx.x * blockDim.x + threadIdx.x;
    int wid = gid >> 6, lane = threadIdx.x & 63;
    int nw = (gridDim.x * blockDim.x) >> 6;
    int g = lane >> 4;
    float as0 = asrc[4 * lane], as1 = asrc[4 * lane + 1];
    float as2 = asrc[4 * lane + 2], as3 = asrc[4 * lane + 3];
    float ad0 = adst[4 * lane], ad1 = adst[4 * lane + 1];
    float ad2 = adst[4 * lane + 2], ad3 = adst[4 * lane + 3];
    for (int i = wid; i < N; i += nw) {
        ushort4 u = *(const ushort4*)&hb[(size_t)i * 256 + 4 * lane];
        float v0 = bf2f(u.x), v1 = bf2f(u.y), v2 = bf2f(u.z), v3 = bf2f(u.w);
        float s = v0 * as0 + v1 * as1 + v2 * as2 + v3 * as3;
        float d = v0 * ad0 + v1 * ad1 + v2 * ad2 + v3 * ad3;
#pragma unroll
        for (int m = 8; m >= 1; m >>= 1) {
            s += __shfl_xor(s, m);
            d += __shfl_xor(d, m);
        }
        if ((lane & 15) == 0) { sv[i * 4 + g] = s; dv[i * 4 + g] = d; }
    }
}

__global__ void sd1_kernel(const ushort* __restrict__ hb, const float* __restrict__ asrc,
                           const float* __restrict__ adst, float* __restrict__ sv,
                           float* __restrict__ dv, int N) {
    int gid = blockIdx.x * blockDim.x + threadIdx.x;
    int wid = gid >> 6, lane = threadIdx.x & 63;
    int nw = (gridDim.x * blockDim.x) >> 6;
    float a = asrc[lane], b = adst[lane];
    for (int i = wid; i < N; i += nw) {
        float v = bf2f(hb[(size_t)i * 64 + lane]);
        float s = v * a, d = v * b;
#pragma unroll
        for (int m = 32; m >= 1; m >>= 1) {
            s += __shfl_xor(s, m);
            d += __shfl_xor(d, m);
        }
        if (lane == 0) { sv[i] = s; dv[i] = d; }
    }
}

// ---------------- aggregation ----------------
// H=4: 128 threads/block, thread t owns channels {2t,2t+1} (one bf16x2 load
// per edge), group g=t>>5 == head; reductions within 32-lane groups.

__launch_bounds__(128)
__global__ void agg4_kernel(const ushort* __restrict__ hb, const float* __restrict__ sv,
                            const float* __restrict__ dv, const int* __restrict__ offsets,
                            const int* __restrict__ srcs, const float* __restrict__ bias,
                            ushort* __restrict__ zb, int N) {
    int i = blockIdx.x;
    int t = threadIdx.x, g = t >> 5, gl = t & 31;
    int beg = offsets[i], end = offsets[i + 1];

    float d_i = dv[i * 4 + g];
    float e_self = lrelu(sv[i * 4 + g] + d_i);

    float mx = e_self;
    for (int j = beg + gl; j < end; j += 32)
        mx = fmaxf(mx, lrelu(sv[srcs[j] * 4 + g] + d_i));
#pragma unroll
    for (int m = 16; m >= 1; m >>= 1) mx = fmaxf(mx, __shfl_xor(mx, m));

    float den = 0.f;
    for (int j = beg + gl; j < end; j += 32)
        den += __expf(lrelu(sv[srcs[j] * 4 + g] + d_i) - mx);
#pragma unroll
    for (int m = 16; m >= 1; m >>= 1) den += __shfl_xor(den, m);
    float wself = __expf(e_self - mx);
    den += wself + 1e-16f;
    float rden = 1.f / den;

    uint p = *(const uint*)&hb[(size_t)i * 256 + 2 * t];
    float ax = wself * bf2f(p & 0xffffu);
    float ay = wself * bf2f(p >> 16);
    for (int j = beg; j < end; ++j) {
        int srcn = srcs[j];
        float wgt = __expf(lrelu(sv[srcn * 4 + g] + d_i) - mx);
        uint q = *(const uint*)&hb[(size_t)srcn * 256 + 2 * t];
        ax += wgt * bf2f(q & 0xffffu);
        ay += wgt * bf2f(q >> 16);
    }
    ax = ax * rden + bias[2 * t];
    ay = ay * rden + bias[2 * t + 1];
    *(uint*)&zb[(size_t)i * 256 + 2 * t] = (uint)f2bf(ax) | ((uint)f2bf(ay) << 16);
}

__launch_bounds__(64)
__global__ void agg1_kernel(const ushort* __restrict__ hb, const float* __restrict__ sv,
                            const float* __restrict__ dv, const int* __restrict__ offsets,
                            const int* __restrict__ srcs, const float* __restrict__ bias,
                            ushort* __restrict__ zb, int N) {
    int i = blockIdx.x;
    int lane = threadIdx.x;
    int beg = offsets[i], end = offsets[i + 1];

    float d_i = dv[i];
    float e_self = lrelu(sv[i] + d_i);

    float mx = e_self;
    for (int j = beg + lane; j < end; j += 64)
        mx = fmaxf(mx, lrelu(sv[srcs[j]] + d_i));
#pragma unroll
    for (int m = 32; m >= 1; m >>= 1) mx = fmaxf(mx, __shfl_xor(mx, m));

    float den = 0.f;
    for (int j = beg + lane; j < end; j += 64)
        den += __expf(lrelu(sv[srcs[j]] + d_i) - mx);
#pragma unroll
    for (int m = 32; m >= 1; m >>= 1) den += __shfl_xor(den, m);
    float wself = __expf(e_self - mx);
    den += wself + 1e-16f;
    float rden = 1.f / den;

    float acc = wself * bf2f(hb[(size_t)i * 64 + lane]);
    for (int j = beg; j < end; ++j) {
        int srcn = srcs[j];
        float wgt = __expf(lrelu(sv[srcn] + d_i) - mx);
        acc += wgt * bf2f(hb[(size_t)srcn * 64 + lane]);
    }
    zb[(size_t)i * 64 + lane] = f2bf(acc * rden + bias[lane]);
}

// ---------------- BatchNorm (bf16 in/out, fp32 stats) ----------------

__global__ void bn_stats_kernel(const ushort* __restrict__ x, float* __restrict__ sums,
                                float* __restrict__ sumsq, int N, int F) {
    int t = threadIdx.x;
    int col = t % F;
    int rg = t / F;
    int RG = blockDim.x / F;
    int rows_per = (N + gridDim.x - 1) / gridDim.x;
    int r0 = blockIdx.x * rows_per;
    int r1 = min(N, r0 + rows_per);
    float s = 0.f, q = 0.f;
    for (int r = r0 + rg; r < r1; r += RG) {
        float v = bf2f(x[(size_t)r * F + col]);
        s += v; q += v * v;
    }
    __shared__ float ls[256], lq[256];
    ls[t] = s; lq[t] = q;
    __syncthreads();
    if (t < F) {
        for (int g = 1; g < RG; ++g) { s += ls[t + g * F]; q += lq[t + g * F]; }
        atomicAdd(&sums[t], s);
        atomicAdd(&sumsq[t], q);
    }
}

__global__ void bn_final_kernel(const float* __restrict__ sums, const float* __restrict__ sumsq,
                                const float* __restrict__ g, const float* __restrict__ be,
                                float* __restrict__ scale, float* __restrict__ shift,
                                int N, int F) {
    int t = threadIdx.x;
    if (t < F) {
        float mean = sums[t] / (float)N;
        float var = sumsq[t] / (float)N - mean * mean;
        float sc = g[t] * rsqrtf(var + BN_EPS);
        scale[t] = sc;
        shift[t] = be[t] - sc * mean;
    }
}

// processes bf16 pairs (uint) in-place, ReLU fused
__global__ void bn_apply_kernel(uint* __restrict__ x, const float* __restrict__ scale,
                                const float* __restrict__ shift, int totalPairs, int Fmask) {
    int i = blockIdx.x * blockDim.x + threadIdx.x;
    if (i < totalPairs) {
        uint p = x[i];
        int c0 = (2 * i) & Fmask;
        float v0 = bf2f(p & 0xffffu) * scale[c0] + shift[c0];
        float v1 = bf2f(p >> 16) * scale[c0 + 1] + shift[c0 + 1];
        v0 = fmaxf(v0, 0.f);
        v1 = fmaxf(v1, 0.f);
        x[i] = (uint)f2bf(v0) | ((uint)f2bf(v1) << 16);
    }
}

// ---------------- pooling + classifier ----------------

__global__ void pool_kernel(const ushort* __restrict__ x, float* __restrict__ psum,
                            float* __restrict__ pmax, int N) {
    const int F = 64;
    int t = threadIdx.x;
    int col = t & 63;
    int rg = t >> 6;
    const int RG = 4;
    int rows_per = (N + gridDim.x - 1) / gridDim.x;
    int r0 = blockIdx.x * rows_per;
    int r1 = min(N, r0 + rows_per);
    float s = 0.f, m = 0.f;
    for (int r = r0 + rg; r < r1; r += RG) {
        float v = bf2f(x[(size_t)r * F + col]);
        s += v; m = fmaxf(m, v);
    }
    __shared__ float ls[256], lm[256];
    ls[t] = s; lm[t] = m;
    __syncthreads();
    if (t < F) {
        for (int g = 1; g < RG; ++g) { s += ls[t + g * F]; m = fmaxf(m, lm[t + g * F]); }
        atomicAdd(&psum[t], s);
        atomicMax((unsigned int*)&pmax[t], __float_as_uint(m));
    }
}

__global__ void classify_kernel(const float* __restrict__ psum, const float* __restrict__ pmax,
                                const float* __restrict__ Wc1, const float* __restrict__ bc1,
                                const float* __restrict__ Wc2, const float* __restrict__ bc2,
                                float* __restrict__ out, int N) {
    __shared__ float pooled[128];
    __shared__ float z[64];
    int t = threadIdx.x;   // 128 threads
    if (t < 64) pooled[t] = psum[t] / (float)N;
    else pooled[t] = pmax[t - 64];
    __syncthreads();
    if (t < 64) {
        float a = bc1[t];
        for (int k = 0; k < 128; ++k) a += pooled[k] * Wc1[k * 64 + t];
        z[t] = a > 0.f ? a : 0.f;
    }
    __syncthreads();
    if (t < 2) {
        float a = bc2[t];
        for (int j = 0; j < 64; ++j) a += z[j] * Wc2[j * 2 + t];
        out[t] = a;
    }
}

// ---------------- driver ----------------

extern "C" void kernel_launch(void* const* d_in, const int* in_sizes, int n_in,
                              void* d_out, int out_size, void* d_ws, size_t ws_size,
                              hipStream_t stream) {
    const float* x   = (const float*)d_in[0];
    const int*   ei  = (const int*)d_in[1];
    const float* W0  = (const float*)d_in[2];  const float* b0  = (const float*)d_in[3];
    const float* as0 = (const float*)d_in[4];  const float* ad0 = (const float*)d_in[5];
    const float* g0  = (const float*)d_in[6];  const float* be0 = (const float*)d_in[7];
    const float* W1  = (const float*)d_in[8];  const float* b1  = (const float*)d_in[9];
    const float* as1 = (const float*)d_in[10]; const float* ad1 = (const float*)d_in[11];
    const float* g1  = (const float*)d_in[12]; const float* be1 = (const float*)d_in[13];
    const float* W2  = (const float*)d_in[14]; const float* b2  = (const float*)d_in[15];
    const float* as2 = (const float*)d_in[16]; const float* ad2 = (const float*)d_in[17];
    const float* g2  = (const float*)d_in[18]; const float* be2 = (const float*)d_in[19];
    const float* Wc1 = (const float*)d_in[20]; const float* bc1 = (const float*)d_in[21];
    const float* Wc2 = (const float*)d_in[22]; const float* bc2 = (const float*)d_in[23];
    float* out = (float*)d_out;

    const int N = in_sizes[0] / 128;            // 50000
    const int E = in_sizes[1] / 2;              // 800000
    const int Mpad = ((N + 127) / 128) * 128;   // 50048

    char* ws = (char*)d_ws;
    size_t o = 0;
    auto alloc = [&](size_t bytes) -> void* {
        void* p = ws + o;
        o = (o + bytes + 255) & ~(size_t)255;
        return p;
    };
    int*    deg     = (int*)alloc((size_t)N * 4);
    int*    offsets = (int*)alloc((size_t)(N + 1) * 4);
    int*    cursor  = (int*)alloc((size_t)N * 4);
    int*    srcs    = (int*)alloc((size_t)E * 4);
    ushort* xb      = (ushort*)alloc((size_t)Mpad * 128 * 2);
    ushort* w0t     = (ushort*)alloc((size_t)256 * 128 * 2);
    ushort* w1t     = (ushort*)alloc((size_t)256 * 256 * 2);
    ushort* w2t     = (ushort*)alloc((size_t)64 * 256 * 2);
    ushort* hb      = (ushort*)alloc((size_t)Mpad * 256 * 2);
    ushort* zb      = (ushort*)alloc((size_t)Mpad * 256 * 2);
    float*  sv      = (float*)alloc((size_t)N * 4 * 4);
    float*  dv      = (float*)alloc((size_t)N * 4 * 4);
    float*  bnsum   = (float*)alloc(256 * 4);
    float*  bnsq    = (float*)alloc(256 * 4);
    float*  scale   = (float*)alloc(256 * 4);
    float*  shift   = (float*)alloc(256 * 4);
    float*  psum    = (float*)alloc(64 * 4);
    float*  pmax    = (float*)alloc(64 * 4);

    // ---- CSR by destination ----
    hipMemsetAsync(deg, 0, (size_t)N * 4, stream);
    int eb = (E + 255) / 256;
    hist_kernel<<<eb, 256, 0, stream>>>(ei, deg, E);
    scan_kernel<<<1, 1024, 0, stream>>>(deg, offsets, cursor, N);
    scatter_kernel<<<eb, 256, 0, stream>>>(ei, cursor, srcs, E);

    // ---- conversions ----
    cvt_x_kernel<<<(Mpad * 128 + 255) / 256, 256, 0, stream>>>(x, xb, N * 128, Mpad * 128);
    transpose_w_kernel<<<(128 * 256 + 255) / 256, 256, 0, stream>>>(W0, w0t, 128, 256);
    transpose_w_kernel<<<(256 * 256 + 255) / 256, 256, 0, stream>>>(W1, w1t, 256, 256);
    transpose_w_kernel<<<(256 * 64 + 255) / 256, 256, 0, stream>>>(W2, w2t, 256, 64);

    auto bn_block = [&](int F, const float* gamma, const float* beta) {
        hipMemsetAsync(bnsum, 0, F * 4, stream);
        hipMemsetAsync(bnsq, 0, F * 4, stream);
        bn_stats_kernel<<<256, 256, 0, stream>>>(zb, bnsum, bnsq, N, F);
        bn_final_kernel<<<1, F, 0, stream>>>(bnsum, bnsq, gamma, beta, scale, shift, N, F);
        int pairs = N * F / 2;
        bn_apply_kernel<<<(pairs + 255) / 256, 256, 0, stream>>>((uint*)zb, scale, shift,
                                                                 pairs, F - 1);
    };

    // ---- layer 0: xb[Mpad,128] -> hb[Mpad,256] -> zb ----
    {
        dim3 gg(Mpad / 128, 2);
        mfma_gemm_bt<128><<<gg, 256, 0, stream>>>(xb, w0t, hb, 128, 256);
        sd4_kernel<<<512, 256, 0, stream>>>(hb, as0, ad0, sv, dv, N);
        agg4_kernel<<<N, 128, 0, stream>>>(hb, sv, dv, offsets, srcs, b0, zb, N);
        bn_block(256, g0, be0);
    }
    // ---- layer 1: zb[Mpad,256] -> hb[Mpad,256] -> zb ----
    {
        dim3 gg(Mpad / 128, 2);
        mfma_gemm_bt<128><<<gg, 256, 0, stream>>>(zb, w1t, hb, 256, 256);
        sd4_kernel<<<512, 256, 0, stream>>>(hb, as1, ad1, sv, dv, N);
        agg4_kernel<<<N, 128, 0, stream>>>(hb, sv, dv, offsets, srcs, b1, zb, N);
        bn_block(256, g1, be1);
    }
    // ---- layer 2: zb[Mpad,256] -> hb[Mpad,64] -> zb[.,64] ----
    {
        dim3 gg(Mpad / 128, 1);
        mfma_gemm_bt<64><<<gg, 256, 0, stream>>>(zb, w2t, hb, 256, 64);
        sd1_kernel<<<512, 256, 0, stream>>>(hb, as2, ad2, sv, dv, N);
        agg1_kernel<<<N, 64, 0, stream>>>(hb, sv, dv, offsets, srcs, b2, zb, N);
        bn_block(64, g2, be2);
    }

    // ---- pooling + classifier ----
    hipMemsetAsync(psum, 0, 64 * 4, stream);
    hipMemsetAsync(pmax, 0, 64 * 4, stream);
    pool_kernel<<<256, 256, 0, stream>>>(zb, psum, pmax, N);
    classify_kernel<<<1, 128, 0, stream>>>(psum, pmax, Wc1, bc1, Wc2, bc2, out, N);
}